// Round 9
// baseline (805.427 us; speedup 1.0000x reference)
//
#include <hip/hip_runtime.h>
#include <hip/hip_fp16.h>

#define NN 50000
#define NE 300000
#define ETILES (NE / 16)
#define NTILES (NN / 16)
#define WLDS_STRIDE 136
#define BKT 128
#define NB 391
#define NB1 392
#define NCH 74
#define CHSZ 4096
#define HSTR 68

typedef _Float16 f16;
typedef _Float16 f16x4 __attribute__((ext_vector_type(4)));
typedef float f32x4 __attribute__((ext_vector_type(4)));

struct Idx6 { const int* p[6]; };
struct FA { const float* x[3]; const int* idx[6]; const float* attr[6]; };

__device__ __forceinline__ f16x4 cvt4(float4 v) {
    f16x4 r; r.x = (f16)v.x; r.y = (f16)v.y; r.z = (f16)v.z; r.w = (f16)v.w;
    return r;
}

// ---------------- init: xh = x (f16), 3 levels ----------------
__global__ void init_xh_kernel(const float* __restrict__ x0, const float* __restrict__ x1,
                               const float* __restrict__ x2, f16* __restrict__ xhbase) {
    const size_t i = (size_t)blockIdx.x * 256 + threadIdx.x;   // 9375*256 == 3*NN*16
    const int lvl = (int)(i / (NN * 16));
    const size_t li = i - (size_t)lvl * (NN * 16);
    const float* xs = (lvl == 0) ? x0 : (lvl == 1) ? x1 : x2;
    float4 v = ((const float4*)xs)[li];
    ((f16x4*)(xhbase + (size_t)lvl * NN * 64))[li] = cvt4(v);
}

// ---------------- init (fallback): h = 2*x AND xh = x ----------------
__global__ void init2_kernel(const float* __restrict__ x0, const float* __restrict__ x1,
                             const float* __restrict__ x2,
                             f16* __restrict__ hbase, f16* __restrict__ xhbase) {
    const size_t i = (size_t)blockIdx.x * 256 + threadIdx.x;
    const int lvl = (int)(i / (NN * 16));
    const size_t li = i - (size_t)lvl * (NN * 16);
    const float* xs = (lvl == 0) ? x0 : (lvl == 1) ? x1 : x2;
    float4 v = ((const float4*)xs)[li];
    f16x4 xo, ho;
    xo.x = (f16)v.x;        xo.y = (f16)v.y;        xo.z = (f16)v.z;        xo.w = (f16)v.w;
    ho.x = (f16)(2.f*v.x);  ho.y = (f16)(2.f*v.y);  ho.z = (f16)(2.f*v.z);  ho.w = (f16)(2.f*v.w);
    ((f16x4*)(xhbase + (size_t)lvl * NN * 64))[li] = xo;
    ((f16x4*)(hbase  + (size_t)lvl * NN * 64))[li] = ho;
}

// ---------------- W transposes to f16 ----------------
__global__ void wtrans_kernel(const float* __restrict__ WU, const float* __restrict__ WD,
                              f16* __restrict__ WtU, f16* __restrict__ WtD) {
    const int i = blockIdx.x * 256 + threadIdx.x;   // 8192
    const int k = i >> 6, c = i & 63;
    WtU[c * 128 + k] = (f16)WU[i];
    WtD[c * 128 + k] = (f16)WD[i];
}

__global__ void w12trans_kernel(const float* __restrict__ W1, const float* __restrict__ W2,
                                f16* __restrict__ W1t, f16* __restrict__ W2t) {
    const int i = blockIdx.x * 256 + threadIdx.x;   // 4096
    const int k = i >> 6, c = i & 63;
    W1t[c * 64 + k] = (f16)W1[i];
    W2t[c * 64 + k] = (f16)W2[i];
}

// ================= bucketed edge-list build =================
__global__ void hist_b_kernel(Idx6 idx, int* __restrict__ cntBC) {
    __shared__ int c[NB];
    const int t = threadIdx.x, ch = blockIdx.x, d = blockIdx.y;
    for (int i = t; i < NB; i += 256) c[i] = 0;
    __syncthreads();
    const int base = ch * CHSZ;
    const int* tg = idx.p[d];
#pragma unroll
    for (int i = 0; i < 16; ++i) {
        const int e = base + i * 256 + t;
        if (e < NE) atomicAdd(&c[tg[e] >> 7], 1);
    }
    __syncthreads();
    for (int i = t; i < NB; i += 256) cntBC[(d * NB + i) * NCH + ch] = c[i];
}

__global__ void scan_b_kernel(const int* __restrict__ cntBC, int* __restrict__ offBC,
                              int* __restrict__ rowptrB) {
    __shared__ int sb[512];
    const int t = threadIdx.x, d = blockIdx.x;
    int tot = 0;
    if (t < NB)
        for (int c = 0; c < NCH; ++c) tot += cntBC[(d * NB + t) * NCH + c];
    sb[t] = tot; __syncthreads();
#pragma unroll
    for (int off = 1; off < 512; off <<= 1) {
        int v = (t >= off) ? sb[t - off] : 0;
        __syncthreads();
        sb[t] += v;
        __syncthreads();
    }
    const int excl = sb[t] - tot;
    if (t < NB) {
        rowptrB[d * NB1 + t] = excl;
        int run = excl;
        for (int c = 0; c < NCH; ++c) {
            offBC[(d * NB + t) * NCH + c] = run;
            run += cntBC[(d * NB + t) * NCH + c];
        }
        if (t == NB - 1) rowptrB[d * NB1 + NB] = run;
    }
}

__global__ void write_eids_b_kernel(Idx6 idx, const int* __restrict__ offBC,
                                    int* __restrict__ eids) {
    __shared__ int cur[NB];
    const int t = threadIdx.x, ch = blockIdx.x, d = blockIdx.y;
    for (int i = t; i < NB; i += 256) cur[i] = offBC[(d * NB + i) * NCH + ch];
    __syncthreads();
    const int base = ch * CHSZ;
    const int* tg = idx.p[d];
#pragma unroll
    for (int i = 0; i < 16; ++i) {
        const int e = base + i * 256 + t;
        if (e < NE) {
            const int p = atomicAdd(&cur[tg[e] >> 7], 1);
            eids[(size_t)d * NE + p] = e;
        }
    }
}

// ================= THE fused kernel: edges->LDS h + node MLP =================
__global__ __launch_bounds__(512) void fused_kernel(
    FA fa, const f16* __restrict__ xhbase,
    const f16* __restrict__ WtU, const f16* __restrict__ WtD,
    const float* __restrict__ bU, const float* __restrict__ bD,
    const int* __restrict__ eids, const int* __restrict__ rowptrB,
    const f16* __restrict__ W1t, const f16* __restrict__ W2t,
    const float* __restrict__ b1, const float* __restrict__ b2,
    float* __restrict__ outb) {

    __shared__ float hl[BKT * HSTR];   // 34.8 KB
    __shared__ f16 Y[8][16 * 72];      // 18 KB

    const int lvl  = blockIdx.y;
    const int bkt  = blockIdx.x;
    const int base = bkt * BKT;
    const int tid  = threadIdx.x;
    const int lane = tid & 63;
    const int w    = tid >> 6;          // 0..7
    const int lr   = lane & 15;
    const int lg   = (lane >> 4) & 3;

    const float* x  = fa.x[lvl];
    const f16*   xh = xhbase + (size_t)lvl * NN * 64;
    float*       out = outb + (size_t)lvl * NN * 64;

    // init h bucket = 2*x
    for (int i = tid; i < BKT * 16; i += 512) {
        const int nl = i >> 4, c4 = i & 15;
        float4 v = make_float4(0.f, 0.f, 0.f, 0.f);
        if (base + nl < NN) v = ((const float4*)x)[(size_t)(base + nl) * 16 + c4];
        ((float4*)&hl[nl * HSTR])[c4] = make_float4(2.f*v.x, 2.f*v.y, 2.f*v.z, 2.f*v.w);
    }
    __syncthreads();

    for (int dir = 0; dir < 2; ++dir) {
        const int d = 2 * lvl + dir;
        const int* __restrict__ gidx  = fa.idx[d];
        const float4* __restrict__ a4 = (const float4*)fa.attr[d];
        const f16* __restrict__ Wt    = dir ? WtD : WtU;
        const float* __restrict__ bb  = dir ? bD : bU;
        const int* __restrict__ eid   = eids + (size_t)d * NE;
        const int s0 = rowptrB[d * NB1 + bkt];
        const int s1 = rowptrB[d * NB1 + bkt + 1];
        if (s1 <= s0) continue;
        const int T = (s1 - s0 + 15) >> 4;

        f16x4 wf[8][4];
#pragma unroll
        for (int k0 = 0; k0 < 8; ++k0)
#pragma unroll
            for (int n = 0; n < 4; ++n)
                wf[k0][n] = *(const f16x4*)&Wt[(n * 16 + lr) * 128 + k0 * 16 + 4 * lg];
        float bf[4];
#pragma unroll
        for (int n = 0; n < 4; ++n) bf[n] = bb[n * 16 + lr];

        if (w < T) {
            // 3-stage pipeline state
            int eA, sA, gA, gB;
            float4 aB[4]; f16x4 xB[4];
            {   // loadA(tile w)
                const int sb = s0 + w * 16;
                const int sl = (sb + lr < s1 - 1) ? (sb + lr) : (s1 - 1);
                eA = eid[sl]; sA = gidx[NE + eA]; gA = gidx[eA];
            }
            {   // loadB(tile w)
#pragma unroll
                for (int k0 = 0; k0 < 4; ++k0) aB[k0] = a4[(size_t)eA * 16 + 4 * k0 + lg];
#pragma unroll
                for (int k0 = 0; k0 < 4; ++k0)
                    xB[k0] = *(const f16x4*)&xh[(size_t)sA * 64 + k0 * 16 + 4 * lg];
                gB = gA;
            }
            {   // loadA(tile w+8), clamped
                const int t2 = (w + 8 < T) ? (w + 8) : w;
                const int sb = s0 + t2 * 16;
                const int sl = (sb + lr < s1 - 1) ? (sb + lr) : (s1 - 1);
                eA = eid[sl]; sA = gidx[NE + eA]; gA = gidx[eA];
            }
            for (int t = w; t < T; t += 8) {
                // issue loadB(t+8) from stage-A regs
                float4 aN[4]; f16x4 xN[4]; const int gN = gA;
#pragma unroll
                for (int k0 = 0; k0 < 4; ++k0) aN[k0] = a4[(size_t)eA * 16 + 4 * k0 + lg];
#pragma unroll
                for (int k0 = 0; k0 < 4; ++k0)
                    xN[k0] = *(const f16x4*)&xh[(size_t)sA * 64 + k0 * 16 + 4 * lg];
                // issue loadA(t+16)
                {
                    const int t2 = (t + 16 < T) ? (t + 16) : t;
                    const int sb = s0 + t2 * 16;
                    const int sl = (sb + lr < s1 - 1) ? (sb + lr) : (s1 - 1);
                    eA = eid[sl]; sA = gidx[NE + eA]; gA = gidx[eA];
                }
                // compute(t)
                {
                    const int sb = s0 + t * 16;
                    f16x4 afr[8];
#pragma unroll
                    for (int k0 = 0; k0 < 4; ++k0) afr[k0] = xB[k0];
#pragma unroll
                    for (int k0 = 0; k0 < 4; ++k0) afr[4 + k0] = cvt4(aB[k0]);
                    f32x4 acc[4];
#pragma unroll
                    for (int n = 0; n < 4; ++n) acc[n] = (f32x4){0.f, 0.f, 0.f, 0.f};
#pragma unroll
                    for (int k0 = 0; k0 < 8; ++k0)
#pragma unroll
                        for (int n = 0; n < 4; ++n)
                            acc[n] = __builtin_amdgcn_mfma_f32_16x16x16f16(afr[k0], wf[k0][n], acc[n], 0, 0, 0);
#pragma unroll
                    for (int j = 0; j < 4; ++j) {
                        const int row = 4 * lg + j;
                        const int nl  = __shfl(gB, row) - base;
                        const bool ok = (sb + row) < s1;
#pragma unroll
                        for (int n = 0; n < 4; ++n) {
                            const float v = fmaxf(acc[n][j] + bf[n], 0.f);
                            if (ok) atomicAdd(&hl[nl * HSTR + n * 16 + lr], v);
                        }
                    }
                }
                // rotate
#pragma unroll
                for (int k0 = 0; k0 < 4; ++k0) { aB[k0] = aN[k0]; xB[k0] = xN[k0]; }
                gB = gN;
            }
        }
    }
    __syncthreads();

    // node MLP: wave w -> nodes [base + w*16, base + w*16 + 16)
    f16x4 w1f[4][4], w2f[4][4];
#pragma unroll
    for (int k0 = 0; k0 < 4; ++k0)
#pragma unroll
        for (int n = 0; n < 4; ++n) {
            w1f[k0][n] = *(const f16x4*)&W1t[(n * 16 + lr) * 64 + k0 * 16 + 4 * lg];
            w2f[k0][n] = *(const f16x4*)&W2t[(n * 16 + lr) * 64 + k0 * 16 + 4 * lg];
        }
    float b1f[4], b2f[4];
#pragma unroll
    for (int n = 0; n < 4; ++n) { b1f[n] = b1[n * 16 + lr]; b2f[n] = b2[n * 16 + lr]; }

    const int r0 = w * 16;
    f16x4 a[4];
#pragma unroll
    for (int k0 = 0; k0 < 4; ++k0) {
        f16x4 tv;
#pragma unroll
        for (int jj = 0; jj < 4; ++jj)
            tv[jj] = (f16)hl[(r0 + lr) * HSTR + k0 * 16 + 4 * lg + jj];
        a[k0] = tv;
    }
    f32x4 acc[4];
#pragma unroll
    for (int n = 0; n < 4; ++n) acc[n] = (f32x4){0.f, 0.f, 0.f, 0.f};
#pragma unroll
    for (int k0 = 0; k0 < 4; ++k0)
#pragma unroll
        for (int n = 0; n < 4; ++n)
            acc[n] = __builtin_amdgcn_mfma_f32_16x16x16f16(a[k0], w1f[k0][n], acc[n], 0, 0, 0);
#pragma unroll
    for (int n = 0; n < 4; ++n)
#pragma unroll
        for (int j = 0; j < 4; ++j) {
            float v = acc[n][j] + b1f[n];
            v = v > 0.f ? v : 0.f;
            Y[w][(4 * lg + j) * 72 + n * 16 + lr] = (f16)v;
        }
    f16x4 a2[4];
#pragma unroll
    for (int k0 = 0; k0 < 4; ++k0)
        a2[k0] = *(const f16x4*)&Y[w][lr * 72 + k0 * 16 + 4 * lg];
    f32x4 acc2[4];
#pragma unroll
    for (int n = 0; n < 4; ++n) acc2[n] = (f32x4){0.f, 0.f, 0.f, 0.f};
#pragma unroll
    for (int k0 = 0; k0 < 4; ++k0)
#pragma unroll
        for (int n = 0; n < 4; ++n)
            acc2[n] = __builtin_amdgcn_mfma_f32_16x16x16f16(a2[k0], w2f[k0][n], acc2[n], 0, 0, 0);
#pragma unroll
    for (int n = 0; n < 4; ++n)
#pragma unroll
        for (int j = 0; j < 4; ++j) {
            const int node = base + r0 + 4 * lg + j;
            float v = acc2[n][j] + b2f[n];
            v = v > 0.f ? v : 0.f;
            if (node < NN) out[(size_t)node * 64 + n * 16 + lr] = v;
        }
}

// ================= Fallback (round-5 proven): edge MLP + f16 atomic scatter =================
__device__ __forceinline__ int ld_comb(const int* __restrict__ idx, int tile, int l5) {
    const int e0 = tile << 4;
    return idx[(l5 < 16) ? (NE + e0 + l5) : (e0 + l5 - 16)];
}

__global__ __launch_bounds__(256) void edge4_kernel(
    const f16* __restrict__ xh,
    const int* __restrict__ ui, const int* __restrict__ di,
    const float* __restrict__ ua, const float* __restrict__ da,
    const f16* __restrict__ WtU, const f16* __restrict__ WtD,
    const float* __restrict__ bU, const float* __restrict__ bD,
    __half* __restrict__ h) {

    __shared__ __align__(16) f16 Wlds[64 * WLDS_STRIDE];

    const int dir = blockIdx.y;
    const int* __restrict__ idx    = dir ? di : ui;
    const float* __restrict__ attr = dir ? da : ua;
    const f16* __restrict__ Wt     = dir ? WtD : WtU;
    const float* __restrict__ b    = dir ? bD : bU;

    const int tt   = threadIdx.x;
    const int lane = tt & 63;
    const int wid  = tt >> 6;
    const int lr   = lane & 15;
    const int lg   = (lane >> 4) & 3;
    const int l5   = lane & 31;

    for (int i = tt; i < 2048; i += 256) {
        const int row = i >> 5, seg = i & 31;
        *(f16x4*)&Wlds[row * WLDS_STRIDE + seg * 4] = *(const f16x4*)&Wt[row * 128 + seg * 4];
    }
    float bf[4];
#pragma unroll
    for (int n = 0; n < 4; ++n) bf[n] = b[n * 16 + lr];
    __syncthreads();

    const float4* a4 = (const float4*)attr;
    const int S = gridDim.x * 4;
    int t = blockIdx.x * 4 + wid;
    if (t >= ETILES) return;

    for (; t < ETILES; t += S) {
        const int e0 = t << 4;
        const int cA = ld_comb(idx, t, l5);
        const int src = __shfl(cA, lr);
        int tg[4];
#pragma unroll
        for (int j = 0; j < 4; ++j) tg[j] = __shfl(cA, 16 + 4 * lg + j);

        f16x4 afr[8];
#pragma unroll
        for (int k0 = 0; k0 < 4; ++k0)
            afr[k0] = *(const f16x4*)&xh[(size_t)src * 64 + k0 * 16 + 4 * lg];
#pragma unroll
        for (int k0 = 0; k0 < 4; ++k0)
            afr[4 + k0] = cvt4(a4[(size_t)(e0 + lr) * 16 + 4 * k0 + lg]);

        f32x4 acc[4];
#pragma unroll
        for (int n = 0; n < 4; ++n) acc[n] = (f32x4){0, 0, 0, 0};
#pragma unroll
        for (int k0 = 0; k0 < 8; ++k0)
#pragma unroll
            for (int n = 0; n < 4; ++n) {
                const f16x4 wfv = *(const f16x4*)&Wlds[(n * 16 + lr) * WLDS_STRIDE + k0 * 16 + 4 * lg];
                acc[n] = __builtin_amdgcn_mfma_f32_16x16x16f16(afr[k0], wfv, acc[n], 0, 0, 0);
            }

#pragma unroll
        for (int j = 0; j < 4; ++j) {
            float v[4], vn[4];
#pragma unroll
            for (int n = 0; n < 4; ++n) v[n] = fmaxf(acc[n][j] + bf[n], 0.f);
#pragma unroll
            for (int n = 0; n < 4; ++n) vn[n] = __shfl_xor(v[n], 1);
            __half* hp = h + (size_t)tg[j] * 64;
            if ((lane & 1) == 0) {
                unsafeAtomicAdd((__half2*)(hp + 0 * 16 + lr), __floats2half2_rn(v[0], vn[0]));
                unsafeAtomicAdd((__half2*)(hp + 1 * 16 + lr), __floats2half2_rn(v[1], vn[1]));
            } else {
                unsafeAtomicAdd((__half2*)(hp + 2 * 16 + lr - 1), __floats2half2_rn(vn[2], v[2]));
                unsafeAtomicAdd((__half2*)(hp + 3 * 16 + lr - 1), __floats2half2_rn(vn[3], v[3]));
            }
        }
    }
}

__global__ __launch_bounds__(256) void node_kernel(
    const f16* __restrict__ hbase, float* __restrict__ outb,
    const float* __restrict__ W1, const float* __restrict__ b1,
    const float* __restrict__ W2, const float* __restrict__ b2) {

    __shared__ f16 Y[4][16 * 72];

    const int t    = threadIdx.x;
    const int lane = t & 63;
    const int wid  = t >> 6;
    const int lr   = lane & 15;
    const int lg   = (lane >> 4) & 3;

    f16x4 w1f[4][4], w2f[4][4];
#pragma unroll
    for (int k0 = 0; k0 < 4; ++k0) {
        const int kb = k0 * 16 + 4 * lg;
#pragma unroll
        for (int n = 0; n < 4; ++n) {
            const int c = n * 16 + lr;
            f16x4 wv;
            wv.x = (f16)W1[(kb + 0) * 64 + c];
            wv.y = (f16)W1[(kb + 1) * 64 + c];
            wv.z = (f16)W1[(kb + 2) * 64 + c];
            wv.w = (f16)W1[(kb + 3) * 64 + c];
            w1f[k0][n] = wv;
            wv.x = (f16)W2[(kb + 0) * 64 + c];
            wv.y = (f16)W2[(kb + 1) * 64 + c];
            wv.z = (f16)W2[(kb + 2) * 64 + c];
            wv.w = (f16)W2[(kb + 3) * 64 + c];
            w2f[k0][n] = wv;
        }
    }
    float b1f[4], b2f[4];
#pragma unroll
    for (int n = 0; n < 4; ++n) {
        b1f[n] = b1[n * 16 + lr];
        b2f[n] = b2[n * 16 + lr];
    }

    const int gw     = blockIdx.x * 4 + wid;
    const int stride = gridDim.x * 4;
    for (int tile = gw; tile < 3 * NTILES; tile += stride) {
        const int lvl = tile / NTILES;
        const int n0  = (tile - lvl * NTILES) << 4;
        float* out = outb + (size_t)lvl * NN * 64;
        const f16* h16 = hbase + (size_t)lvl * NN * 64;

        f16x4 a[4];
#pragma unroll
        for (int k0 = 0; k0 < 4; ++k0)
            a[k0] = *(const f16x4*)&h16[(size_t)(n0 + lr) * 64 + k0 * 16 + 4 * lg];

        f32x4 acc[4];
#pragma unroll
        for (int n = 0; n < 4; ++n) acc[n] = (f32x4){0, 0, 0, 0};
#pragma unroll
        for (int k0 = 0; k0 < 4; ++k0)
#pragma unroll
            for (int n = 0; n < 4; ++n)
                acc[n] = __builtin_amdgcn_mfma_f32_16x16x16f16(a[k0], w1f[k0][n], acc[n], 0, 0, 0);

#pragma unroll
        for (int n = 0; n < 4; ++n)
#pragma unroll
            for (int j = 0; j < 4; ++j) {
                float v = acc[n][j] + b1f[n];
                v = v > 0.f ? v : 0.f;
                Y[wid][(4 * lg + j) * 72 + n * 16 + lr] = (f16)v;
            }

        f16x4 a2[4];
#pragma unroll
        for (int k0 = 0; k0 < 4; ++k0)
            a2[k0] = *(const f16x4*)&Y[wid][lr * 72 + k0 * 16 + 4 * lg];

        f32x4 acc2[4];
#pragma unroll
        for (int n = 0; n < 4; ++n) acc2[n] = (f32x4){0, 0, 0, 0};
#pragma unroll
        for (int k0 = 0; k0 < 4; ++k0)
#pragma unroll
            for (int n = 0; n < 4; ++n)
                acc2[n] = __builtin_amdgcn_mfma_f32_16x16x16f16(a2[k0], w2f[k0][n], acc2[n], 0, 0, 0);

#pragma unroll
        for (int n = 0; n < 4; ++n)
#pragma unroll
            for (int j = 0; j < 4; ++j) {
                float v = acc2[n][j] + b2f[n];
                v = v > 0.f ? v : 0.f;
                out[(size_t)(n0 + 4 * lg + j) * 64 + n * 16 + lr] = v;
            }
    }
}

extern "C" void kernel_launch(void* const* d_in, const int* in_sizes, int n_in,
                              void* d_out, int out_size, void* d_ws, size_t ws_size,
                              hipStream_t stream) {
    (void)in_sizes; (void)n_in; (void)out_size;

    const float* W_up   = (const float*)d_in[15];
    const float* b_up   = (const float*)d_in[16];
    const float* W_down = (const float*)d_in[17];
    const float* b_down = (const float*)d_in[18];
    const float* W1     = (const float*)d_in[19];
    const float* b1     = (const float*)d_in[20];
    const float* W2     = (const float*)d_in[21];
    const float* b2     = (const float*)d_in[22];

    const float* x0 = (const float*)d_in[0];
    const float* x1 = (const float*)d_in[5];
    const float* x2 = (const float*)d_in[10];

    size_t off = 0;
    auto alloc = [&](size_t bytes) { size_t o = off; off = (off + bytes + 255) & ~(size_t)255; return o; };
    const size_t o_xh    = alloc((size_t)3 * NN * 64 * 2);
    const size_t o_agg   = alloc((size_t)3 * NN * 64 * 2);     // fallback h only
    const size_t o_wt    = alloc((size_t)2 * 128 * 64 * 2);
    const size_t fallback_need = off;
    const size_t o_w12   = alloc((size_t)2 * 64 * 64 * 2);
    const size_t o_cnt   = alloc((size_t)6 * NB * NCH * 4);
    const size_t o_off   = alloc((size_t)6 * NB * NCH * 4);
    const size_t o_rpB   = alloc((size_t)6 * NB1 * 4);
    const size_t o_eid   = alloc((size_t)6 * NE * 4);
    const size_t full_need = off;

    char* ws = (char*)d_ws;
    f16* xh  = (f16*)(ws + o_xh);
    f16* agg = (f16*)(ws + o_agg);
    f16* WtU = (f16*)(ws + o_wt);
    f16* WtD = WtU + 128 * 64;

    Idx6 idx;
    FA fa;
    for (int d = 0; d < 3; ++d) {
        fa.x[d] = (const float*)d_in[5 * d + 0];
        idx.p[2 * d + 0] = fa.idx[2 * d + 0] = (const int*)d_in[5 * d + 1];
        idx.p[2 * d + 1] = fa.idx[2 * d + 1] = (const int*)d_in[5 * d + 2];
        fa.attr[2 * d + 0] = (const float*)d_in[5 * d + 3];
        fa.attr[2 * d + 1] = (const float*)d_in[5 * d + 4];
    }

    if (ws_size >= full_need) {
        f16* W1t = (f16*)(ws + o_w12);
        f16* W2t = W1t + 64 * 64;
        int* cntBC   = (int*)(ws + o_cnt);
        int* offBC   = (int*)(ws + o_off);
        int* rowptrB = (int*)(ws + o_rpB);
        int* eids    = (int*)(ws + o_eid);

        wtrans_kernel<<<32, 256, 0, stream>>>(W_up, W_down, WtU, WtD);
        w12trans_kernel<<<16, 256, 0, stream>>>(W1, W2, W1t, W2t);
        init_xh_kernel<<<9375, 256, 0, stream>>>(x0, x1, x2, xh);

        hist_b_kernel<<<dim3(NCH, 6), 256, 0, stream>>>(idx, cntBC);
        scan_b_kernel<<<6, 512, 0, stream>>>(cntBC, offBC, rowptrB);
        write_eids_b_kernel<<<dim3(NCH, 6), 256, 0, stream>>>(idx, offBC, eids);

        fused_kernel<<<dim3(NB, 3), 512, 0, stream>>>(
            fa, xh, WtU, WtD, b_up, b_down, eids, rowptrB,
            W1t, W2t, b1, b2, (float*)d_out);
    } else if (ws_size >= fallback_need) {
        wtrans_kernel<<<32, 256, 0, stream>>>(W_up, W_down, WtU, WtD);
        init2_kernel<<<9375, 256, 0, stream>>>(x0, x1, x2, agg, xh);
        for (int d = 0; d < 3; ++d) {
            const int*   ui = (const int*)  d_in[5 * d + 1];
            const int*   di = (const int*)  d_in[5 * d + 2];
            const float* ua = (const float*)d_in[5 * d + 3];
            const float* da = (const float*)d_in[5 * d + 4];
            const f16* xhd = xh + (size_t)d * NN * 64;
            __half* h = (__half*)(agg + (size_t)d * NN * 64);
            edge4_kernel<<<dim3(1024, 2), 256, 0, stream>>>(
                xhd, ui, di, ua, da, WtU, WtD, b_up, b_down, h);
        }
        node_kernel<<<586, 256, 0, stream>>>(agg, (float*)d_out, W1, b1, W2, b2);
    }
}